// Round 1
// baseline (420.129 us; speedup 1.0000x reference)
//
#include <hip/hip_runtime.h>
#include <hip/hip_bf16.h>
#include <math.h>

#define B_N 8192
#define D_K 256
#define TILE 128
#define BK 32
#define NT 256
#define LDSTRIDE 40  // 32 + 8 shorts pad: 80B rows keep 16B alignment, 2-way-max bank aliasing

typedef __attribute__((ext_vector_type(8))) short short8;
typedef __attribute__((ext_vector_type(4))) float f32x4;

__device__ __forceinline__ unsigned short f2bf(float x) {
    unsigned int u = __float_as_uint(x);
    unsigned int r = (u + 0x7FFFu + ((u >> 16) & 1u)) >> 16;
    return (unsigned short)r;
}

// -------- Kernel 1: per-row inverse L2 norm --------
__global__ void norm_kernel(const float* __restrict__ feat, float* __restrict__ inv_norm) {
    int row = blockIdx.x;
    float v = feat[(size_t)row * D_K + threadIdx.x];
    float ss = v * v;
    #pragma unroll
    for (int off = 32; off; off >>= 1) ss += __shfl_down(ss, off);
    __shared__ float acc[4];
    if ((threadIdx.x & 63) == 0) acc[threadIdx.x >> 6] = ss;
    __syncthreads();
    if (threadIdx.x == 0) {
        float t = acc[0] + acc[1] + acc[2] + acc[3];
        inv_norm[row] = 1.0f / fmaxf(sqrtf(t), 1e-12f);
    }
}

// -------- Kernel 2: tiled sim + streaming row reductions --------
// Per-row ws accumulators: denom_sum (Σ_{j≠i} e^{sim-20}), pos_sum (Σ_pos sim),
// n_pos, relax_sum (Σ_{high} e^{sim-20}), n_high, sim_max (as int bits, init 0).
__global__ __launch_bounds__(NT) void main_kernel(
        const float* __restrict__ feat, const int* __restrict__ labels,
        const float* __restrict__ inv_norm,
        float* __restrict__ denom, float* __restrict__ pos_sum,
        float* __restrict__ n_pos, float* __restrict__ relax,
        float* __restrict__ n_high, int* __restrict__ smax) {
    __shared__ short As[TILE * LDSTRIDE];
    __shared__ short Bs[TILE * LDSTRIDE];
    __shared__ int Ls[2 * TILE];  // [0,128): row labels, [128,256): col labels

    const int tid = threadIdx.x;
    const int row0 = blockIdx.y * TILE;
    const int col0 = blockIdx.x * TILE;
    const int lane = tid & 63, wave = tid >> 6;
    const int wm = wave >> 1, wn = wave & 1;  // 2x2 waves, each 64x64
    const int l15 = lane & 15, lhi = lane >> 4;

    if (tid < 128) Ls[tid] = labels[row0 + tid];
    else Ls[tid] = labels[col0 + tid - 128];

    f32x4 acc[4][4];
    #pragma unroll
    for (int i = 0; i < 4; i++)
        #pragma unroll
        for (int j = 0; j < 4; j++) acc[i][j] = {0.f, 0.f, 0.f, 0.f};

    for (int kc = 0; kc < D_K / BK; ++kc) {
        #pragma unroll
        for (int li = 0; li < 4; ++li) {
            int id = tid + li * NT;        // 0..1023 over 128 rows x 8 float4-quads
            int r = id >> 3, q = id & 7;
            const float4 va = *(const float4*)(feat + (size_t)(row0 + r) * D_K + kc * BK + q * 4);
            float sa = inv_norm[row0 + r];
            short4 pa;
            pa.x = (short)f2bf(va.x * sa); pa.y = (short)f2bf(va.y * sa);
            pa.z = (short)f2bf(va.z * sa); pa.w = (short)f2bf(va.w * sa);
            *(short4*)&As[r * LDSTRIDE + q * 4] = pa;
            const float4 vb = *(const float4*)(feat + (size_t)(col0 + r) * D_K + kc * BK + q * 4);
            float sb = inv_norm[col0 + r];
            short4 pb;
            pb.x = (short)f2bf(vb.x * sb); pb.y = (short)f2bf(vb.y * sb);
            pb.z = (short)f2bf(vb.z * sb); pb.w = (short)f2bf(vb.w * sb);
            *(short4*)&Bs[r * LDSTRIDE + q * 4] = pb;
        }
        __syncthreads();
        // A lane layout (16x16x32): A[m = lane&15][k = (lane>>4)*8 + j]; B mirrors with n = lane&15
        short8 af[4], bfr[4];
        #pragma unroll
        for (int mi = 0; mi < 4; mi++)
            af[mi] = *(const short8*)&As[(wm * 64 + mi * 16 + l15) * LDSTRIDE + lhi * 8];
        #pragma unroll
        for (int ni = 0; ni < 4; ni++)
            bfr[ni] = *(const short8*)&Bs[(wn * 64 + ni * 16 + l15) * LDSTRIDE + lhi * 8];
        #pragma unroll
        for (int mi = 0; mi < 4; mi++)
            #pragma unroll
            for (int ni = 0; ni < 4; ni++)
                acc[mi][ni] = __builtin_amdgcn_mfma_f32_16x16x32_bf16(af[mi], bfr[ni], acc[mi][ni], 0, 0, 0);
        __syncthreads();
    }

    // Epilogue. C/D layout: col = lane&15, row = (lane>>4)*4 + reg  [m89-verified]
    int lc[4], colg[4];
    #pragma unroll
    for (int ni = 0; ni < 4; ni++) {
        int c = wn * 64 + ni * 16 + l15;
        lc[ni] = Ls[128 + c];
        colg[ni] = col0 + c;
    }
    #pragma unroll
    for (int mi = 0; mi < 4; mi++) {
        #pragma unroll
        for (int reg = 0; reg < 4; reg++) {
            int rloc = wm * 64 + mi * 16 + lhi * 4 + reg;
            int rowg = row0 + rloc;
            int lr = Ls[rloc];
            float d_acc = 0.f, p_acc = 0.f, np_acc = 0.f, rx_acc = 0.f, nh_acc = 0.f, mx = -1e30f;
            #pragma unroll
            for (int ni = 0; ni < 4; ni++) {
                float sim = acc[mi][ni][reg] * 20.0f;   // dot / temperature
                float e = __expf(sim - 20.0f);          // fixed shift = 1/T (valid: sim <= 20)
                bool self = (rowg == colg[ni]);
                bool pos = (!self) && (lr == lc[ni]);
                mx = fmaxf(mx, sim);
                if (!self) d_acc += e;
                if (pos) {
                    p_acc += sim; np_acc += 1.0f;
                    if (sim > 14.0f) { rx_acc += e; nh_acc += 1.0f; }  // sim*T > 0.7
                }
            }
            // reduce across the 16 lanes (same row, different cols)
            #pragma unroll
            for (int off = 1; off < 16; off <<= 1) {
                d_acc += __shfl_xor(d_acc, off);
                p_acc += __shfl_xor(p_acc, off);
                np_acc += __shfl_xor(np_acc, off);
                rx_acc += __shfl_xor(rx_acc, off);
                nh_acc += __shfl_xor(nh_acc, off);
                mx = fmaxf(mx, __shfl_xor(mx, off));
            }
            if (l15 == 0) {
                atomicAdd(&denom[rowg], d_acc);
                if (np_acc > 0.f) {
                    atomicAdd(&pos_sum[rowg], p_acc);
                    atomicAdd(&n_pos[rowg], np_acc);
                }
                if (nh_acc > 0.f) {
                    atomicAdd(&relax[rowg], rx_acc);
                    atomicAdd(&n_high[rowg], nh_acc);
                }
                if (mx > 0.f) atomicMax(&smax[rowg], __float_as_int(mx));  // pos-float int-order trick
            }
        }
    }
}

// -------- Kernel 3: final scalar reduction --------
__global__ void finalize_kernel(const float* __restrict__ denom, const float* __restrict__ pos_sum,
                                const float* __restrict__ n_pos, const float* __restrict__ relax,
                                const float* __restrict__ n_high, const int* __restrict__ smax,
                                float* __restrict__ out) {
    double scl = 0.0, npos = 0.0, rlx = 0.0, nhigh = 0.0;
    for (int r = threadIdx.x; r < B_N; r += 256) {
        float np = n_pos[r];
        float ld = logf(denom[r] + 1e-12f) + 20.0f;  // log_denom with shift 20
        scl += (double)(np * ld - pos_sum[r]);
        npos += (double)np;
        float nh = n_high[r];
        nhigh += (double)nh;
        if (nh > 0.f) {
            float sm = __int_as_float(smax[r]);
            rlx += (double)(logf(relax[r] + 1.0f) + (20.0f - sm));
        }
    }
    #pragma unroll
    for (int off = 32; off; off >>= 1) {
        scl += __shfl_down(scl, off);
        npos += __shfl_down(npos, off);
        rlx += __shfl_down(rlx, off);
        nhigh += __shfl_down(nhigh, off);
    }
    __shared__ double sh[4][4];
    int wave = threadIdx.x >> 6, lane = threadIdx.x & 63;
    if (lane == 0) { sh[wave][0] = scl; sh[wave][1] = npos; sh[wave][2] = rlx; sh[wave][3] = nhigh; }
    __syncthreads();
    if (threadIdx.x == 0) {
        double s = 0, n = 0, rl = 0, nh = 0;
        for (int w = 0; w < 4; w++) { s += sh[w][0]; n += sh[w][1]; rl += sh[w][2]; nh += sh[w][3]; }
        double scl_loss = (n > 0.0) ? s / fmax(n, 1.0) : 0.0;
        double rel_loss = (nh > 0.0) ? rl / fmax(nh, 1.0) : 0.0;
        double tot = scl_loss + 1.0 * rel_loss;  // BETA = 1.0
        tot = fmin(fmax(tot, 0.0), 10.0);
        out[0] = (float)tot;
    }
}

extern "C" void kernel_launch(void* const* d_in, const int* in_sizes, int n_in,
                              void* d_out, int out_size, void* d_ws, size_t ws_size,
                              hipStream_t stream) {
    const float* feat = (const float*)d_in[0];
    const int* labels = (const int*)d_in[1];
    float* out = (float*)d_out;
    char* ws = (char*)d_ws;

    float* inv_norm = (float*)(ws);                 // 32 KB
    float* denom    = (float*)(ws + 32 * 1024);
    float* pos_sum  = (float*)(ws + 64 * 1024);
    float* n_pos    = (float*)(ws + 96 * 1024);
    float* relax    = (float*)(ws + 128 * 1024);
    float* n_high   = (float*)(ws + 160 * 1024);
    int*   smax     = (int*)(ws + 192 * 1024);      // ends at 224 KB

    hipMemsetAsync(ws + 32 * 1024, 0, 192 * 1024, stream);
    norm_kernel<<<B_N, 256, 0, stream>>>(feat, inv_norm);
    main_kernel<<<dim3(B_N / TILE, B_N / TILE), NT, 0, stream>>>(
        feat, labels, inv_norm, denom, pos_sum, n_pos, relax, n_high, smax);
    finalize_kernel<<<1, 256, 0, stream>>>(denom, pos_sum, n_pos, relax, n_high, smax, out);
    (void)in_sizes; (void)n_in; (void)out_size; (void)ws_size;
}

// Round 2
// 199.769 us; speedup vs baseline: 2.1031x; 2.1031x over previous
//
#include <hip/hip_runtime.h>
#include <hip/hip_bf16.h>
#include <math.h>

#define B_N 8192
#define D_K 256
#define TILE 128
#define NT 256
#define NBLK 64             // B_N / TILE
#define NPAIR 2080          // NBLK*(NBLK+1)/2 upper-triangular tile pairs
#define LDA 72              // 64 cols + 8 shorts pad: row stride 144B (16B-aligned, even bank spread)
#define KEXP 28.8539008177792681f   // 20 * log2(e): e^(sim-20) = 2^((dot-1)*KEXP), sim = 20*dot

typedef __attribute__((ext_vector_type(8))) short short8;
typedef __attribute__((ext_vector_type(4))) float f32x4;

__device__ __forceinline__ unsigned short f2bf(float x) {
    unsigned int u = __float_as_uint(x);
    unsigned int r = (u + 0x7FFFu + ((u >> 16) & 1u)) >> 16;
    return (unsigned short)r;
}

// -------- Kernel 1: normalize rows + convert to bf16, once --------
// 1 wave per row: lane loads float4 (256 floats = 64 lanes x 4), xor-reduce, write 4 bf16.
__global__ void prep_kernel(const float* __restrict__ feat, unsigned short* __restrict__ fnorm) {
    int wave = threadIdx.x >> 6, lane = threadIdx.x & 63;
    int row = blockIdx.x * 4 + wave;
    float4 v = *(const float4*)(feat + (size_t)row * D_K + lane * 4);
    float ss = v.x * v.x + v.y * v.y + v.z * v.z + v.w * v.w;
    #pragma unroll
    for (int off = 1; off < 64; off <<= 1) ss += __shfl_xor(ss, off);
    float inv = 1.0f / fmaxf(sqrtf(ss), 1e-12f);
    ushort4 o;
    o.x = f2bf(v.x * inv); o.y = f2bf(v.y * inv);
    o.z = f2bf(v.z * inv); o.w = f2bf(v.w * inv);
    *(ushort4*)(fnorm + (size_t)row * D_K + lane * 4) = o;
}

// -------- Kernel 2: upper-triangular sim tiles, symmetric reuse, streaming partials --------
// G[slot j][row r] = float4{denom_e_sum, n_pos, relax_e_sum, max_dot}; each slot written exactly once.
__global__ __launch_bounds__(NT) void main_kernel(
        const unsigned short* __restrict__ fnorm, const int* __restrict__ labels,
        float4* __restrict__ G, float* __restrict__ gscal) {
    // decode linear block id -> (a <= b) triangular pair
    int bid = blockIdx.x;
    int b = (int)((sqrtf(8.0f * bid + 1.0f) - 1.0f) * 0.5f);
    while ((b + 1) * (b + 2) / 2 <= bid) ++b;
    while (b * (b + 1) / 2 > bid) --b;
    int a = bid - b * (b + 1) / 2;
    const int row0 = a * TILE, col0 = b * TILE;
    const bool diag = (a == b);

    __shared__ short As[TILE * LDA];   // 18432 B (reused as Rbuf in epilogue)
    __shared__ short Bs[TILE * LDA];   // 18432 B (reused as Cbuf in epilogue)
    __shared__ int Ls[2 * TILE];
    __shared__ float sc[4][2];

    const int tid = threadIdx.x;
    const int lane = tid & 63, wave = tid >> 6;
    const int wm = wave >> 1, wn = wave & 1;    // 2x2 waves, each 64x64
    const int l15 = lane & 15, lhi = lane >> 4;
    const short* fn = (const short*)fnorm;

    if (tid < 128) Ls[tid] = labels[row0 + tid];
    else Ls[tid] = labels[col0 + tid - 128];

    f32x4 acc[4][4];
    #pragma unroll
    for (int i = 0; i < 4; i++)
        #pragma unroll
        for (int j = 0; j < 4; j++) acc[i][j] = {0.f, 0.f, 0.f, 0.f};

    // K loop: BK=64, 4 chunks, bf16 staged directly (no conversion)
    for (int kc = 0; kc < 4; ++kc) {
        #pragma unroll
        for (int li = 0; li < 4; ++li) {
            int id = tid + li * NT;           // 0..1023 over 128 rows x 8 16B-chunks
            int r = id >> 3, c8 = id & 7;
            *(short8*)&As[r * LDA + c8 * 8] =
                *(const short8*)&fn[(size_t)(row0 + r) * D_K + kc * 64 + c8 * 8];
            *(short8*)&Bs[r * LDA + c8 * 8] =
                *(const short8*)&fn[(size_t)(col0 + r) * D_K + kc * 64 + c8 * 8];
        }
        __syncthreads();
        #pragma unroll
        for (int ks = 0; ks < 2; ++ks) {
            short8 af[4], bfr[4];
            #pragma unroll
            for (int mi = 0; mi < 4; mi++)
                af[mi] = *(const short8*)&As[(wm * 64 + mi * 16 + l15) * LDA + ks * 32 + lhi * 8];
            #pragma unroll
            for (int ni = 0; ni < 4; ni++)
                bfr[ni] = *(const short8*)&Bs[(wn * 64 + ni * 16 + l15) * LDA + ks * 32 + lhi * 8];
            #pragma unroll
            for (int mi = 0; mi < 4; mi++)
                #pragma unroll
                for (int ni = 0; ni < 4; ni++)
                    acc[mi][ni] = __builtin_amdgcn_mfma_f32_16x16x32_bf16(af[mi], bfr[ni], acc[mi][ni], 0, 0, 0);
        }
        __syncthreads();
    }

    // ---- Epilogue. C/D layout: col = lane&15, row = (lane>>4)*4 + reg ----
    float* Rbuf = (float*)As;   // [wn][128][4]
    float* Cbuf = (float*)Bs;   // [wm][128][4]

    int lc[4], colg[4];
    #pragma unroll
    for (int ni = 0; ni < 4; ni++) {
        int c = wn * 64 + ni * 16 + l15;
        lc[ni] = Ls[128 + c];
        colg[ni] = col0 + c;
    }

    float cD[4] = {0.f, 0.f, 0.f, 0.f}, cN[4] = {0.f, 0.f, 0.f, 0.f};
    float cR[4] = {0.f, 0.f, 0.f, 0.f}, cM[4] = {-1e30f, -1e30f, -1e30f, -1e30f};
    float gp = 0.f, gh = 0.f;

    #pragma unroll
    for (int mi = 0; mi < 4; mi++) {
        #pragma unroll
        for (int reg = 0; reg < 4; reg++) {
            int rloc = wm * 64 + mi * 16 + lhi * 4 + reg;
            int rowg = row0 + rloc;
            int lr = Ls[rloc];
            float d = 0.f, np = 0.f, rx = 0.f, mx = -1e30f;
            #pragma unroll
            for (int ni = 0; ni < 4; ni++) {
                float dot = acc[mi][ni][reg];
                float e = __builtin_exp2f((dot - 1.0f) * KEXP);   // e^(sim-20), sim<=20 always
                bool self = (rowg == colg[ni]);
                bool pos = (!self) && (lr == lc[ni]);
                bool high = pos && (dot > 0.7f);                  // sim*T > 0.7  <=>  dot > 0.7
                float ev = self ? 0.f : e;
                float pv = pos ? 1.f : 0.f;
                float hv = high ? e : 0.f;
                d += ev; np += pv; rx += hv;
                mx = fmaxf(mx, dot);
                gp += pos ? dot : 0.f;
                gh += high ? 1.f : 0.f;
                cD[ni] += ev; cN[ni] += pv; cR[ni] += hv;
                cM[ni] = fmaxf(cM[ni], dot);
            }
            // row-direction: reduce across 16 cols (l15 lanes)
            #pragma unroll
            for (int off = 1; off < 16; off <<= 1) {
                d += __shfl_xor(d, off);
                np += __shfl_xor(np, off);
                rx += __shfl_xor(rx, off);
                mx = fmaxf(mx, __shfl_xor(mx, off));
            }
            if (l15 == 0) {
                float* p = &Rbuf[(wn * 128 + rloc) * 4];
                p[0] = d; p[1] = np; p[2] = rx; p[3] = mx;
            }
        }
    }

    // column-direction (transpose reuse), off-diagonal tiles only
    if (!diag) {
        #pragma unroll
        for (int ni = 0; ni < 4; ni++) {
            #pragma unroll
            for (int off = 16; off < 64; off <<= 1) {
                cD[ni] += __shfl_xor(cD[ni], off);
                cN[ni] += __shfl_xor(cN[ni], off);
                cR[ni] += __shfl_xor(cR[ni], off);
                cM[ni] = fmaxf(cM[ni], __shfl_xor(cM[ni], off));
            }
        }
        if (lhi == 0) {
            #pragma unroll
            for (int ni = 0; ni < 4; ni++) {
                int c = wn * 64 + ni * 16 + l15;
                float* p = &Cbuf[(wm * 128 + c) * 4];
                p[0] = cD[ni]; p[1] = cN[ni]; p[2] = cR[ni]; p[3] = cM[ni];
            }
        }
    }

    // global scalars: sum(pos dot), count(high) — 2 atomics per block
    #pragma unroll
    for (int off = 1; off < 64; off <<= 1) {
        gp += __shfl_xor(gp, off);
        gh += __shfl_xor(gh, off);
    }
    if (lane == 0) { sc[wave][0] = gp; sc[wave][1] = gh; }
    __syncthreads();

    // combine wn (resp. wm) halves and stream out exactly-once float4 per (slot,row)
    if (tid < 128) {
        int r = tid;
        float4 o;
        o.x = Rbuf[(0 * 128 + r) * 4 + 0] + Rbuf[(1 * 128 + r) * 4 + 0];
        o.y = Rbuf[(0 * 128 + r) * 4 + 1] + Rbuf[(1 * 128 + r) * 4 + 1];
        o.z = Rbuf[(0 * 128 + r) * 4 + 2] + Rbuf[(1 * 128 + r) * 4 + 2];
        o.w = fmaxf(Rbuf[(0 * 128 + r) * 4 + 3], Rbuf[(1 * 128 + r) * 4 + 3]);
        G[(size_t)b * B_N + row0 + r] = o;
    } else if (!diag) {
        int c = tid - 128;
        float4 o;
        o.x = Cbuf[(0 * 128 + c) * 4 + 0] + Cbuf[(1 * 128 + c) * 4 + 0];
        o.y = Cbuf[(0 * 128 + c) * 4 + 1] + Cbuf[(1 * 128 + c) * 4 + 1];
        o.z = Cbuf[(0 * 128 + c) * 4 + 2] + Cbuf[(1 * 128 + c) * 4 + 2];
        o.w = fmaxf(Cbuf[(0 * 128 + c) * 4 + 3], Cbuf[(1 * 128 + c) * 4 + 3]);
        G[(size_t)a * B_N + col0 + c] = o;
    }
    if (tid == 0) {
        float w = diag ? 1.0f : 2.0f;   // off-diag tiles stand for both (i,j) and (j,i)
        atomicAdd(&gscal[0], w * (sc[0][0] + sc[1][0] + sc[2][0] + sc[3][0]));
        atomicAdd(&gscal[1], w * (sc[0][1] + sc[1][1] + sc[2][1] + sc[3][1]));
    }
}

// -------- Kernel 3: per-row reduction over 64 slots --------
__global__ void finalize1(const float4* __restrict__ G, double* __restrict__ part) {
    int r = blockIdx.x * 256 + threadIdx.x;
    float d = 0.f, np = 0.f, rx = 0.f, mx = -1e30f;
    for (int j = 0; j < NBLK; ++j) {
        float4 g = G[(size_t)j * B_N + r];
        d += g.x; np += g.y; rx += g.z; mx = fmaxf(mx, g.w);
    }
    float ld = logf(d + 1e-12f) + 20.0f;                         // log_denom
    double s1 = (double)np * (double)ld;                          // sum n_pos_i * log_denom_i
    double s2 = (double)np;                                       // sum n_pos_i
    double s3 = (rx > 0.f) ? (double)(logf(rx + 1.0f) + (20.0f - 20.0f * mx)) : 0.0;  // row_lse if row_has
    #pragma unroll
    for (int off = 1; off < 64; off <<= 1) {
        s1 += __shfl_xor(s1, off);
        s2 += __shfl_xor(s2, off);
        s3 += __shfl_xor(s3, off);
    }
    __shared__ double sh[4][3];
    int wave = threadIdx.x >> 6, lane = threadIdx.x & 63;
    if (lane == 0) { sh[wave][0] = s1; sh[wave][1] = s2; sh[wave][2] = s3; }
    __syncthreads();
    if (threadIdx.x == 0) {
        part[blockIdx.x * 3 + 0] = sh[0][0] + sh[1][0] + sh[2][0] + sh[3][0];
        part[blockIdx.x * 3 + 1] = sh[0][1] + sh[1][1] + sh[2][1] + sh[3][1];
        part[blockIdx.x * 3 + 2] = sh[0][2] + sh[1][2] + sh[2][2] + sh[3][2];
    }
}

// -------- Kernel 4: scalar assembly --------
__global__ void finalize2(const double* __restrict__ part, const float* __restrict__ gscal,
                          float* __restrict__ out) {
    if (threadIdx.x == 0) {
        double s1 = 0, s2 = 0, s3 = 0;
        for (int b = 0; b < 32; ++b) {
            s1 += part[b * 3 + 0];
            s2 += part[b * 3 + 1];
            s3 += part[b * 3 + 2];
        }
        double gp = (double)gscal[0];   // sum over pos pairs of dot
        double gh = (double)gscal[1];   // count of high pairs
        double scl = (s2 > 0.0) ? (s1 - 20.0 * gp) / fmax(s2, 1.0) : 0.0;
        double rel = (gh > 0.0) ? s3 / fmax(gh, 1.0) : 0.0;
        double tot = scl + rel;         // BETA = 1.0
        tot = fmin(fmax(tot, 0.0), 10.0);
        out[0] = (float)tot;
    }
}

extern "C" void kernel_launch(void* const* d_in, const int* in_sizes, int n_in,
                              void* d_out, int out_size, void* d_ws, size_t ws_size,
                              hipStream_t stream) {
    const float* feat = (const float*)d_in[0];
    const int* labels = (const int*)d_in[1];
    float* out = (float*)d_out;
    char* ws = (char*)d_ws;

    unsigned short* fnorm = (unsigned short*)(ws);                     // 4 MB
    float4* G       = (float4*)(ws + (size_t)4 * 1024 * 1024);         // 8 MB: [64 slots][8192 rows]
    double* part    = (double*)(ws + (size_t)12 * 1024 * 1024);        // 32*3 doubles
    float*  gscal   = (float*)(ws + (size_t)12 * 1024 * 1024 + 4096);  // 2 floats

    hipMemsetAsync(gscal, 0, 2 * sizeof(float), stream);
    prep_kernel<<<B_N / 4, 256, 0, stream>>>(feat, fnorm);
    main_kernel<<<NPAIR, NT, 0, stream>>>(fnorm, labels, G, gscal);
    finalize1<<<B_N / 256, 256, 0, stream>>>(G, part);
    finalize2<<<1, 64, 0, stream>>>(part, gscal, out);
    (void)in_sizes; (void)n_in; (void)out_size; (void)ws_size;
}

// Round 3
// 150.051 us; speedup vs baseline: 2.7999x; 1.3313x over previous
//
#include <hip/hip_runtime.h>
#include <hip/hip_bf16.h>
#include <math.h>

#define B_N 8192
#define D_K 256
#define TILE 128
#define NT 256
#define NBLK 64             // B_N / TILE
#define NPAIR 2080          // NBLK*(NBLK+1)/2 upper-triangular tile pairs
#define NCLS 100
#define LDA 72              // 64 cols + 8 shorts pad: row stride 144B (16B-aligned)
#define KEXP 28.8539008177792681f   // 20*log2(e): e^(sim-20) = 2^((dot-1)*KEXP)

typedef __attribute__((ext_vector_type(8))) short short8;
typedef __attribute__((ext_vector_type(4))) float f32x4;

__device__ __forceinline__ unsigned short f2bf(float x) {
    unsigned int u = __float_as_uint(x);
    unsigned int r = (u + 0x7FFFu + ((u >> 16) & 1u)) >> 16;
    return (unsigned short)r;
}

// -------- Kernel 1: normalize rows -> bf16 matrix + inv_norm --------
__global__ void prep_kernel(const float* __restrict__ feat, unsigned short* __restrict__ fnorm,
                            float* __restrict__ inv_norm) {
    int wave = threadIdx.x >> 6, lane = threadIdx.x & 63;
    int row = blockIdx.x * 4 + wave;
    float4 v = *(const float4*)(feat + (size_t)row * D_K + lane * 4);
    float ss = v.x * v.x + v.y * v.y + v.z * v.z + v.w * v.w;
    #pragma unroll
    for (int off = 1; off < 64; off <<= 1) ss += __shfl_xor(ss, off);
    float inv = 1.0f / fmaxf(sqrtf(ss), 1e-12f);
    if (lane == 0) inv_norm[row] = inv;
    ushort4 o;
    o.x = f2bf(v.x * inv); o.y = f2bf(v.y * inv);
    o.z = f2bf(v.z * inv); o.w = f2bf(v.w * inv);
    *(ushort4*)(fnorm + (size_t)row * D_K + lane * 4) = o;
}

// -------- Kernel 2: per-class counts + sum(pos dots) via class-sum vectors --------
// gp = sum_c (||S_c||^2 - |c|) = sum over ordered same-label pairs (i!=j) of dot_ij  [fp32 exact path]
__global__ void hist_kernel(const float* __restrict__ feat, const int* __restrict__ labels,
                            const float* __restrict__ inv_norm,
                            int* __restrict__ cnt, float* __restrict__ gscal) {
    int c = blockIdx.x, tid = threadIdx.x;
    __shared__ unsigned short list[B_N];
    __shared__ int cntS;
    __shared__ float red[4];
    if (tid == 0) cntS = 0;
    __syncthreads();
    for (int r = tid; r < B_N; r += 256)
        if (labels[r] == c) { int p = atomicAdd(&cntS, 1); list[p] = (unsigned short)r; }
    __syncthreads();
    int n = cntS;
    float s = 0.f;                      // S_c[tid] : dim = tid
    for (int k = 0; k < n; ++k) {
        int r = list[k];
        s += feat[(size_t)r * D_K + tid] * inv_norm[r];
    }
    float v = s * s;
    #pragma unroll
    for (int off = 1; off < 64; off <<= 1) v += __shfl_xor(v, off);
    if ((tid & 63) == 0) red[tid >> 6] = v;
    __syncthreads();
    if (tid == 0) {
        float tot = red[0] + red[1] + red[2] + red[3];
        cnt[c] = n;
        atomicAdd(&gscal[0], tot - (float)n);
    }
}

// -------- Kernel 3: upper-triangular sim tiles, streaming float2 partials --------
// G[slot][row] = {denom_e_sum, relax_e_sum}; each (slot,row) written exactly once.
__global__ __launch_bounds__(NT, 4) void main_kernel(
        const unsigned short* __restrict__ fnorm, const int* __restrict__ labels,
        float2* __restrict__ G, float* __restrict__ gscal) {
    int bid = blockIdx.x;
    int b = (int)((sqrtf(8.0f * bid + 1.0f) - 1.0f) * 0.5f);
    while ((b + 1) * (b + 2) / 2 <= bid) ++b;
    while (b * (b + 1) / 2 > bid) --b;
    int a = bid - b * (b + 1) / 2;
    const int row0 = a * TILE, col0 = b * TILE;
    const bool diag = (a == b);

    __shared__ short As[TILE * LDA];   // reused as Rbuf (float2[2][128]) in epilogue
    __shared__ short Bs[TILE * LDA];   // reused as Cbuf
    __shared__ int Ls[2 * TILE];
    __shared__ int ghs[4];

    const int tid = threadIdx.x;
    const int lane = tid & 63, wave = tid >> 6;
    const int wm = wave >> 1, wn = wave & 1;    // 2x2 waves, each 64x64
    const int l15 = lane & 15, lhi = lane >> 4;
    const short* fn = (const short*)fnorm;

    if (tid < 128) Ls[tid] = labels[row0 + tid];
    else Ls[tid] = labels[col0 + tid - 128];

    f32x4 acc[4][4];
    #pragma unroll
    for (int i = 0; i < 4; i++)
        #pragma unroll
        for (int j = 0; j < 4; j++) acc[i][j] = {0.f, 0.f, 0.f, 0.f};

    for (int kc = 0; kc < 4; ++kc) {
        #pragma unroll
        for (int li = 0; li < 4; ++li) {
            int id = tid + li * NT;
            int r = id >> 3, c8 = id & 7;
            *(short8*)&As[r * LDA + c8 * 8] =
                *(const short8*)&fn[(size_t)(row0 + r) * D_K + kc * 64 + c8 * 8];
            *(short8*)&Bs[r * LDA + c8 * 8] =
                *(const short8*)&fn[(size_t)(col0 + r) * D_K + kc * 64 + c8 * 8];
        }
        __syncthreads();
        #pragma unroll
        for (int ks = 0; ks < 2; ++ks) {
            short8 af[4], bfr[4];
            #pragma unroll
            for (int mi = 0; mi < 4; mi++)
                af[mi] = *(const short8*)&As[(wm * 64 + mi * 16 + l15) * LDA + ks * 32 + lhi * 8];
            #pragma unroll
            for (int ni = 0; ni < 4; ni++)
                bfr[ni] = *(const short8*)&Bs[(wn * 64 + ni * 16 + l15) * LDA + ks * 32 + lhi * 8];
            #pragma unroll
            for (int mi = 0; mi < 4; mi++)
                #pragma unroll
                for (int ni = 0; ni < 4; ni++)
                    acc[mi][ni] = __builtin_amdgcn_mfma_f32_16x16x32_bf16(af[mi], bfr[ni], acc[mi][ni], 0, 0, 0);
        }
        __syncthreads();
    }

    // ---- Epilogue. C/D layout: col = lane&15, row = (lane>>4)*4 + reg ----
    float2* Rbuf = (float2*)As;   // [wn][128]
    float2* Cbuf = (float2*)Bs;   // [wm][128]

    int lc[4], colg[4];
    #pragma unroll
    for (int ni = 0; ni < 4; ni++) {
        int c = wn * 64 + ni * 16 + l15;
        lc[ni] = Ls[128 + c];
        colg[ni] = col0 + c;
    }

    float cD[4] = {0.f, 0.f, 0.f, 0.f}, cR[4] = {0.f, 0.f, 0.f, 0.f};
    int nhi = 0;

    #pragma unroll
    for (int mi = 0; mi < 4; mi++) {
        #pragma unroll
        for (int reg = 0; reg < 4; reg++) {
            int rloc = wm * 64 + mi * 16 + lhi * 4 + reg;
            int rowg = row0 + rloc;
            int lr = Ls[rloc];
            float d = 0.f, rx = 0.f;
            #pragma unroll
            for (int ni = 0; ni < 4; ni++) {
                float dot = acc[mi][ni][reg];
                float e = __builtin_exp2f((dot - 1.0f) * KEXP);   // e^(sim-20), sim<=20
                bool notself = (rowg != colg[ni]);                // only differs on diag tiles
                bool high = (lr == lc[ni]) && (dot > 0.7f) && notself;
                float ev = notself ? e : 0.f;
                float hv = high ? e : 0.f;
                d += ev; rx += hv;
                cD[ni] += ev; cR[ni] += hv;
                nhi += (int)__popcll(__ballot(high));
            }
            #pragma unroll
            for (int off = 1; off < 16; off <<= 1) {
                d += __shfl_xor(d, off);
                rx += __shfl_xor(rx, off);
            }
            if (l15 == 0) Rbuf[wn * 128 + rloc] = {d, rx};
        }
    }

    if (!diag) {
        #pragma unroll
        for (int ni = 0; ni < 4; ni++) {
            #pragma unroll
            for (int off = 16; off < 64; off <<= 1) {
                cD[ni] += __shfl_xor(cD[ni], off);
                cR[ni] += __shfl_xor(cR[ni], off);
            }
        }
        if (lhi == 0) {
            #pragma unroll
            for (int ni = 0; ni < 4; ni++) {
                int c = wn * 64 + ni * 16 + l15;
                Cbuf[wm * 128 + c] = {cD[ni], cR[ni]};
            }
        }
    }
    if (lane == 0) ghs[wave] = nhi;
    __syncthreads();

    if (tid < 128) {
        int r = tid;
        float2 a0 = Rbuf[r], a1 = Rbuf[128 + r];
        G[(size_t)b * B_N + row0 + r] = {a0.x + a1.x, a0.y + a1.y};
    } else if (!diag) {
        int c = tid - 128;
        float2 a0 = Cbuf[c], a1 = Cbuf[128 + c];
        G[(size_t)a * B_N + col0 + c] = {a0.x + a1.x, a0.y + a1.y};
    }
    if (tid == 0) {
        float w = diag ? 1.0f : 2.0f;   // off-diag tile stands for (i,j) and (j,i)
        atomicAdd(&gscal[1], w * (float)(ghs[0] + ghs[1] + ghs[2] + ghs[3]));
    }
}

// -------- Kernel 4: per-row reduction over 64 slots --------
__global__ void finalize1(const float2* __restrict__ G, const int* __restrict__ labels,
                          const int* __restrict__ cnt, double* __restrict__ part) {
    int r = blockIdx.x * 256 + threadIdx.x;
    float d = 0.f, rx = 0.f;
    for (int j = 0; j < NBLK; ++j) {
        float2 g = G[(size_t)j * B_N + r];
        d += g.x; rx += g.y;
    }
    float np = (float)(cnt[labels[r]] - 1);
    float ld = logf(d + 1e-12f) + 20.0f;                 // log_denom (shift 20)
    double s1 = (double)np * (double)ld;
    double s2 = (double)np;
    double s3 = (rx > 0.f) ? (double)logf(rx + 1.0f) : 0.0;  // row_lse: baseline = 0 (sim_max = 20)
    #pragma unroll
    for (int off = 1; off < 64; off <<= 1) {
        s1 += __shfl_xor(s1, off);
        s2 += __shfl_xor(s2, off);
        s3 += __shfl_xor(s3, off);
    }
    __shared__ double sh[4][3];
    int wave = threadIdx.x >> 6, lane = threadIdx.x & 63;
    if (lane == 0) { sh[wave][0] = s1; sh[wave][1] = s2; sh[wave][2] = s3; }
    __syncthreads();
    if (threadIdx.x == 0) {
        part[blockIdx.x * 3 + 0] = sh[0][0] + sh[1][0] + sh[2][0] + sh[3][0];
        part[blockIdx.x * 3 + 1] = sh[0][1] + sh[1][1] + sh[2][1] + sh[3][1];
        part[blockIdx.x * 3 + 2] = sh[0][2] + sh[1][2] + sh[2][2] + sh[3][2];
    }
}

// -------- Kernel 5: scalar assembly --------
__global__ void finalize2(const double* __restrict__ part, const float* __restrict__ gscal,
                          float* __restrict__ out) {
    if (threadIdx.x == 0) {
        double s1 = 0, s2 = 0, s3 = 0;
        for (int b = 0; b < 32; ++b) {
            s1 += part[b * 3 + 0];
            s2 += part[b * 3 + 1];
            s3 += part[b * 3 + 2];
        }
        double gp = (double)gscal[0];   // sum over ordered pos pairs of dot (fp32 path)
        double gh = (double)gscal[1];   // count of high ordered pairs
        double scl = (s2 > 0.0) ? (s1 - 20.0 * gp) / fmax(s2, 1.0) : 0.0;
        double rel = (gh > 0.0) ? s3 / fmax(gh, 1.0) : 0.0;
        double tot = scl + rel;         // BETA = 1.0
        tot = fmin(fmax(tot, 0.0), 10.0);
        out[0] = (float)tot;
    }
}

extern "C" void kernel_launch(void* const* d_in, const int* in_sizes, int n_in,
                              void* d_out, int out_size, void* d_ws, size_t ws_size,
                              hipStream_t stream) {
    const float* feat = (const float*)d_in[0];
    const int* labels = (const int*)d_in[1];
    float* out = (float*)d_out;
    char* ws = (char*)d_ws;

    unsigned short* fnorm = (unsigned short*)(ws);                        // 4 MB
    float2* G        = (float2*)(ws + (size_t)4 * 1024 * 1024);           // 4 MB: [64][8192]
    float*  inv_norm = (float*)(ws + (size_t)8 * 1024 * 1024);            // 32 KB
    double* part     = (double*)(ws + (size_t)8 * 1024 * 1024 + 32768);   // 768 B
    float*  gscal    = (float*)(ws + (size_t)8 * 1024 * 1024 + 36864);    // 8 B
    int*    cnt      = (int*)(ws + (size_t)8 * 1024 * 1024 + 40960);      // 400 B

    hipMemsetAsync(gscal, 0, 2 * sizeof(float), stream);
    prep_kernel<<<B_N / 4, 256, 0, stream>>>(feat, fnorm, inv_norm);
    hist_kernel<<<NCLS, 256, 0, stream>>>(feat, labels, inv_norm, cnt, gscal);
    main_kernel<<<NPAIR, NT, 0, stream>>>(fnorm, labels, G, gscal);
    finalize1<<<B_N / 256, 256, 0, stream>>>(G, labels, cnt, part);
    finalize2<<<1, 64, 0, stream>>>(part, gscal, out);
    (void)in_sizes; (void)n_in; (void)out_size; (void)ws_size;
}